// Round 10
// baseline (180.275 us; speedup 1.0000x reference)
//
#include <hip/hip_runtime.h>
#include <hip/hip_bf16.h>

#define N_NODES 65536
#define N_EDGES 1048576
#define DIM 64
#define NXCD 8
#define PART_BLOCKS 2048                 // 256 blocks per XCD group
#define NODES_PER_GRP (N_NODES / NXCD)   // 8192
#define SLOT_CAP 64                      // P(Poisson(16) >= 64) ~ 2e-18: exact here

typedef float f32x4 __attribute__((ext_vector_type(4)));
typedef unsigned short u16x4 __attribute__((ext_vector_type(4)));

__device__ __forceinline__ float lrelu(float x) { return x >= 0.f ? x : 0.01f * x; }
__device__ __forceinline__ float bf2f(unsigned short h) {
    return __uint_as_float(((unsigned)h) << 16);
}
__device__ __forceinline__ unsigned short f2bf(float f) {
    return __bfloat16_as_ushort(__float2bfloat16(f));  // RNE
}

// ---- prep_scatter: fused {s0/t0 = features.a_src/.a_dst, fbf0 = bf16(features)}
// and XCD-partitioned slotted scatter. nt loads on the dst/src streams and nt
// stores on fbf0 keep the slot+cursor hot set resident in each XCD's L2
// (writeback amplification was L2 stream-pollution, round 9 evidence).
__global__ __launch_bounds__(256) void prep_scatter(
    const float* __restrict__ feats, const float* __restrict__ attn_w,
    const int* __restrict__ src, const int* __restrict__ dst,
    float* __restrict__ s0, float* __restrict__ t0,
    unsigned short* __restrict__ fbf0,
    unsigned* __restrict__ cursor, unsigned short* __restrict__ csr_slot) {
    int tid = threadIdx.x;
    int lane = tid & 63;
    int wave_id = blockIdx.x * 4 + (tid >> 6);   // [0, 8192)
    float aw_s = attn_w[lane];
    float aw_t = attn_w[DIM + lane];
    #pragma unroll
    for (int it = 0; it < 8; ++it) {
        int node = wave_id + it * 8192;
        float f = feats[node * DIM + lane];
        __builtin_nontemporal_store(f2bf(f), &fbf0[node * DIM + lane]);
        float sp = f * aw_s;
        float tq = f * aw_t;
        #pragma unroll
        for (int off = 32; off; off >>= 1) {
            sp += __shfl_xor(sp, off);
            tq += __shfl_xor(tq, off);
        }
        if (lane == 0) { s0[node] = sp; t0[node] = tq; }
    }
    // XCD-partitioned slotted scatter
    int grp = blockIdx.x & (NXCD - 1);
    int blkInGrp = blockIdx.x >> 3;
    int lo = grp * NODES_PER_GRP, hi = lo + NODES_PER_GRP;
    const int stride = (PART_BLOCKS / NXCD) * 256;  // 65536
    for (int e = blkInGrp * 256 + tid; e < N_EDGES; e += stride) {
        int d = __builtin_nontemporal_load(dst + e);
        int sv = __builtin_nontemporal_load(src + e);
        if (d >= lo && d < hi) {
            unsigned pos = atomicAdd(&cursor[d], 1u);
            if (pos < SLOT_CAP) csr_slot[(d << 6) + pos] = (unsigned short)sv;
        }
    }
}

// ---- main aggregation: one wave per dst node, bf16 gathers, slotted CSR ----
// Prologue: tp = t_in[node] (uniform scalar, no reduce). Edge phase: lane j
// owns edge j (deg <= 64, single chunk). Gather: 4 groups of 16 lanes pull
// edges t8+g,+4,+8,+12 as bf16 rows; denominator partials ride the same
// shuffled w values. Group fold packs {acc.xyzw, dn} in 2 xor stages; the
// accumulator stays in l16-chunk layout so the epilogue stores f32x4/u16x4
// directly from lanes 0-15 (no transpose). s_next/t_next: dot4 + 4-stage
// 16-lane reduce. All shuffles convergent; invalid slots self-gate (ev=0).
__global__ __launch_bounds__(256) void node_agg(
    const unsigned short* __restrict__ feats_bf,  // gather source (bf16)
    const float* __restrict__ features_f32,       // exact fown for k==0 out-init
    const float* __restrict__ s_in, const float* __restrict__ t_in,
    const unsigned* __restrict__ deg_arr, const unsigned short* __restrict__ csr_slot,
    const float* __restrict__ attn_w, const float* __restrict__ attn_b,
    const float* __restrict__ temp, int k, int last,
    unsigned short* __restrict__ feats_out_bf,
    float* __restrict__ s_next, float* __restrict__ t_next,
    float* __restrict__ out) {
    int node = blockIdx.x * 4 + (threadIdx.x >> 6);
    int lane = threadIdx.x & 63;
    int g = lane >> 4, l16 = lane & 15;

    float tp = t_in[node];           // wave-uniform
    float b = attn_b[0];
    int deg = min((int)deg_arr[node], SLOT_CAP);

    // edge phase: lane j owns edge j (single chunk, deg <= 64)
    bool valid = lane < deg;
    int sj_l = valid ? (int)__builtin_nontemporal_load(&csr_slot[(node << 6) + lane]) : 0;
    float ev_l = valid ? __expf(lrelu(s_in[sj_l] + tp + b)) : 0.f;

    f32x4 acc = {0.f, 0.f, 0.f, 0.f};
    float dn = 0.f;
    const u16x4* feats4 = (const u16x4*)feats_bf;  // 16 u16x4 per row
    for (int t8 = 0; t8 < deg; t8 += 16) {  // wave-uniform trip count
        int i0 = t8 + g;
        int   sj0 = __shfl(sj_l, i0);
        float w0  = __shfl(ev_l, i0);
        int   sj1 = __shfl(sj_l, i0 + 4);
        float w1  = __shfl(ev_l, i0 + 4);
        int   sj2 = __shfl(sj_l, i0 + 8);
        float w2  = __shfl(ev_l, i0 + 8);
        int   sj3 = __shfl(sj_l, i0 + 12);
        float w3  = __shfl(ev_l, i0 + 12);
        u16x4 q0 = feats4[sj0 * 16 + l16];
        u16x4 q1 = feats4[sj1 * 16 + l16];
        u16x4 q2 = feats4[sj2 * 16 + l16];
        u16x4 q3 = feats4[sj3 * 16 + l16];
        acc[0] += w0 * bf2f(q0[0]) + w1 * bf2f(q1[0]) + w2 * bf2f(q2[0]) + w3 * bf2f(q3[0]);
        acc[1] += w0 * bf2f(q0[1]) + w1 * bf2f(q1[1]) + w2 * bf2f(q2[1]) + w3 * bf2f(q3[1]);
        acc[2] += w0 * bf2f(q0[2]) + w1 * bf2f(q1[2]) + w2 * bf2f(q2[2]) + w3 * bf2f(q3[2]);
        acc[3] += w0 * bf2f(q0[3]) + w1 * bf2f(q1[3]) + w2 * bf2f(q2[3]) + w3 * bf2f(q3[3]);
        dn += w0 + w1 + w2 + w3;
    }
    // fold the 4 edge-groups together; dn rides the same stages.
    // After xor 32 + xor 16, every lane holds the full dn and its l16-chunk acc.
    #pragma unroll
    for (int off = 32; off >= 16; off >>= 1) {
        acc[0] += __shfl_xor(acc[0], off);
        acc[1] += __shfl_xor(acc[1], off);
        acc[2] += __shfl_xor(acc[2], off);
        acc[3] += __shfl_xor(acc[3], off);
        dn     += __shfl_xor(dn, off);
    }
    float inv = (deg > 0) ? 1.f / dn : 0.f;
    f32x4 a4 = acc * inv;

    // epilogue stores from lanes 0-15 (l16-chunk layout, no transpose)
    if (lane < 16) {
        f32x4 o4;
        if (k == 0) {
            f32x4 f4 = ((const f32x4*)features_f32)[node * 16 + l16];
            o4 = temp[0] * f4;
        } else {
            o4 = __builtin_nontemporal_load(&((f32x4*)out)[node * 16 + l16]);
        }
        o4 += temp[k + 1] * a4;
        __builtin_nontemporal_store(o4, &((f32x4*)out)[node * 16 + l16]);
        if (!last) {
            u16x4 ub = {f2bf(a4[0]), f2bf(a4[1]), f2bf(a4[2]), f2bf(a4[3])};
            ((u16x4*)feats_out_bf)[node * 16 + l16] = ub;
        }
    }
    if (!last) {  // fused s/t for next hop (fp32 accumulator, pre-rounding)
        f32x4 aw_s4 = ((const f32x4*)attn_w)[l16];
        f32x4 aw_t4 = ((const f32x4*)attn_w)[16 + l16];
        float sp = a4[0] * aw_s4[0] + a4[1] * aw_s4[1] + a4[2] * aw_s4[2] + a4[3] * aw_s4[3];
        float tq = a4[0] * aw_t4[0] + a4[1] * aw_t4[1] + a4[2] * aw_t4[2] + a4[3] * aw_t4[3];
        #pragma unroll
        for (int off = 1; off < 16; off <<= 1) {
            sp += __shfl_xor(sp, off);
            tq += __shfl_xor(tq, off);
        }
        if (lane == 0) { s_next[node] = sp; t_next[node] = tq; }
    }
}

extern "C" void kernel_launch(void* const* d_in, const int* in_sizes, int n_in,
                              void* d_out, int out_size, void* d_ws, size_t ws_size,
                              hipStream_t stream) {
    const float* features = (const float*)d_in[0];
    const int* src = (const int*)d_in[1];
    const int* dst = (const int*)d_in[2];
    const float* attn_w = (const float*)d_in[3];
    const float* attn_b = (const float*)d_in[4];
    const float* temp = (const float*)d_in[5];
    float* out = (float*)d_out;

    // workspace layout (~27 MB): s0/s1/t0/t1, cursor(=degree), ushort slotted
    // CSR, two bf16 feature buffers (ping-pong fbf0 -> fbfA -> fbf0).
    float* s0 = (float*)d_ws;                          // N
    float* s1 = s0 + N_NODES;                          // N
    float* t0 = s1 + N_NODES;                          // N
    float* t1 = t0 + N_NODES;                          // N
    unsigned* cursor = (unsigned*)(t1 + N_NODES);      // N (degree after scatter)
    unsigned short* csr_slot = (unsigned short*)(cursor + N_NODES);  // N*64 u16 (8 MB)
    unsigned short* fbf0 = csr_slot + (size_t)N_NODES * SLOT_CAP;    // N*DIM bf16
    unsigned short* fbfA = fbf0 + (size_t)N_NODES * DIM;             // N*DIM bf16

    const int NODE_BLOCKS = N_NODES / 4;     // 16384

    hipMemsetAsync(cursor, 0, N_NODES * sizeof(unsigned), stream);
    prep_scatter<<<PART_BLOCKS, 256, 0, stream>>>(features, attn_w, src, dst,
                                                  s0, t0, fbf0, cursor, csr_slot);

    // ---- 3 hops (bf16 gather buffers ping-pong) ----
    node_agg<<<NODE_BLOCKS, 256, 0, stream>>>(fbf0, features, s0, t0, cursor, csr_slot,
                                              attn_w, attn_b, temp, 0, 0,
                                              fbfA, s1, t1, out);
    node_agg<<<NODE_BLOCKS, 256, 0, stream>>>(fbfA, features, s1, t1, cursor, csr_slot,
                                              attn_w, attn_b, temp, 1, 0,
                                              fbf0, s0, t0, out);
    node_agg<<<NODE_BLOCKS, 256, 0, stream>>>(fbf0, features, s0, t0, cursor, csr_slot,
                                              attn_w, attn_b, temp, 2, 1,
                                              fbfA, s1, t1, out);
}

// Round 11
// 155.864 us; speedup vs baseline: 1.1566x; 1.1566x over previous
//
#include <hip/hip_runtime.h>
#include <hip/hip_bf16.h>

#define N_NODES 65536
#define N_EDGES 1048576
#define DIM 64
#define NXCD 8
#define PART_BLOCKS 4096                 // 512 blocks per XCD group
#define NODES_PER_GRP (N_NODES / NXCD)   // 8192
#define SLOT_CAP 64                      // P(Poisson(16) >= 64) ~ 2e-18: exact here

typedef float f32x4 __attribute__((ext_vector_type(4)));
typedef unsigned short u16x4 __attribute__((ext_vector_type(4)));

__device__ __forceinline__ float lrelu(float x) { return x >= 0.f ? x : 0.01f * x; }
__device__ __forceinline__ float bf2f(unsigned short h) {
    return __uint_as_float(((unsigned)h) << 16);
}
__device__ __forceinline__ unsigned short f2bf(float f) {
    return __bfloat16_as_ushort(__float2bfloat16(f));  // RNE
}

// ---- prep_scatter: fused {s0/t0 = features.a_src/.a_dst, fbf0 = bf16(features)}
// and XCD-partitioned slotted scatter (group = blockIdx&7 owns an 8192-node
// dst range; cursor atomics + slot stores stay in that XCD's L2). Plain
// cached loads throughout (r10 lesson: nt hints regressed).
__global__ __launch_bounds__(256) void prep_scatter(
    const float* __restrict__ feats, const float* __restrict__ attn_w,
    const int* __restrict__ src, const int* __restrict__ dst,
    float* __restrict__ s0, float* __restrict__ t0,
    unsigned short* __restrict__ fbf0,
    unsigned* __restrict__ cursor, unsigned short* __restrict__ csr_slot) {
    int tid = threadIdx.x;
    int lane = tid & 63;
    int wave_id = blockIdx.x * 4 + (tid >> 6);   // [0, 16384)
    float aw_s = attn_w[lane];
    float aw_t = attn_w[DIM + lane];
    #pragma unroll
    for (int it = 0; it < 4; ++it) {
        int node = wave_id + it * 16384;
        float f = feats[node * DIM + lane];
        fbf0[node * DIM + lane] = f2bf(f);
        float sp = f * aw_s;
        float tq = f * aw_t;
        #pragma unroll
        for (int off = 32; off; off >>= 1) {
            sp += __shfl_xor(sp, off);
            tq += __shfl_xor(tq, off);
        }
        if (lane == 0) { s0[node] = sp; t0[node] = tq; }
    }
    // XCD-partitioned slotted scatter
    int grp = blockIdx.x & (NXCD - 1);
    int blkInGrp = blockIdx.x >> 3;
    int lo = grp * NODES_PER_GRP, hi = lo + NODES_PER_GRP;
    const int stride = (PART_BLOCKS / NXCD) * 256;  // 131072
    for (int e = blkInGrp * 256 + tid; e < N_EDGES; e += stride) {
        int d = dst[e];
        int sv = src[e];  // unconditional: line ~always touched, coalesced
        if (d >= lo && d < hi) {
            unsigned pos = atomicAdd(&cursor[d], 1u);
            if (pos < SLOT_CAP) csr_slot[(d << 6) + pos] = (unsigned short)sv;
        }
    }
}

// ---- main aggregation: one wave per dst node, bf16 gathers, slotted CSR ----
// Prologue: tp = t_in[node] (wave-uniform scalar load, no reduce). Edge phase:
// lane j owns edge j (deg <= 64, single chunk); packs (bf16(w)<<16 | src_id)
// into ONE u32 so each broadcast slot costs 1 shuffle instead of 2 (w is
// bf16-rounded consistently in numerator and denominator -> exact softmax
// normalization of the rounded weights). Gather: 4 groups of 16 lanes pull
// edges t8+g,+4,+8,+12 as bf16 rows (u16x4 = 4 dims/lane, 128B/row).
// Group fold packs {acc, dn} in 2 xor stages; accumulator stays in l16-chunk
// layout so the epilogue stores f32x4/u16x4 directly from lanes 0-15 (no
// transpose). s_next/t_next: dot4 + 4-stage reduce. All shuffles convergent;
// invalid slots self-gate (w=0, sj=0).
__global__ __launch_bounds__(256) void node_agg(
    const unsigned short* __restrict__ feats_bf,  // gather source (bf16)
    const float* __restrict__ features_f32,       // exact fown for k==0 out-init
    const float* __restrict__ s_in, const float* __restrict__ t_in,
    const unsigned* __restrict__ deg_arr, const unsigned short* __restrict__ csr_slot,
    const float* __restrict__ attn_w, const float* __restrict__ attn_b,
    const float* __restrict__ temp, int k, int last,
    unsigned short* __restrict__ feats_out_bf,
    float* __restrict__ s_next, float* __restrict__ t_next,
    float* __restrict__ out) {
    int node = blockIdx.x * 4 + (threadIdx.x >> 6);
    int lane = threadIdx.x & 63;
    int g = lane >> 4, l16 = lane & 15;

    float tp = t_in[node];           // wave-uniform
    float b = attn_b[0];
    int deg = min((int)deg_arr[node], SLOT_CAP);

    // edge phase: lane j owns edge j (single chunk, deg <= 64)
    bool valid = lane < deg;
    int sj_l = valid ? (int)csr_slot[(node << 6) + lane] : 0;
    float ev_l = valid ? __expf(lrelu(s_in[sj_l] + tp + b)) : 0.f;
    unsigned pk_l = (((unsigned)f2bf(ev_l)) << 16) | (unsigned)sj_l;

    f32x4 acc = {0.f, 0.f, 0.f, 0.f};
    float dn = 0.f;
    const u16x4* feats4 = (const u16x4*)feats_bf;  // 16 u16x4 per row
    for (int t8 = 0; t8 < deg; t8 += 16) {  // wave-uniform trip count
        int i0 = t8 + g;
        unsigned p0 = __shfl(pk_l, i0);
        unsigned p1 = __shfl(pk_l, i0 + 4);
        unsigned p2 = __shfl(pk_l, i0 + 8);
        unsigned p3 = __shfl(pk_l, i0 + 12);
        float w0 = __uint_as_float(p0 & 0xFFFF0000u);
        float w1 = __uint_as_float(p1 & 0xFFFF0000u);
        float w2 = __uint_as_float(p2 & 0xFFFF0000u);
        float w3 = __uint_as_float(p3 & 0xFFFF0000u);
        u16x4 q0 = feats4[(p0 & 0xFFFFu) * 16 + l16];
        u16x4 q1 = feats4[(p1 & 0xFFFFu) * 16 + l16];
        u16x4 q2 = feats4[(p2 & 0xFFFFu) * 16 + l16];
        u16x4 q3 = feats4[(p3 & 0xFFFFu) * 16 + l16];
        acc[0] += w0 * bf2f(q0[0]) + w1 * bf2f(q1[0]) + w2 * bf2f(q2[0]) + w3 * bf2f(q3[0]);
        acc[1] += w0 * bf2f(q0[1]) + w1 * bf2f(q1[1]) + w2 * bf2f(q2[1]) + w3 * bf2f(q3[1]);
        acc[2] += w0 * bf2f(q0[2]) + w1 * bf2f(q1[2]) + w2 * bf2f(q2[2]) + w3 * bf2f(q3[2]);
        acc[3] += w0 * bf2f(q0[3]) + w1 * bf2f(q1[3]) + w2 * bf2f(q2[3]) + w3 * bf2f(q3[3]);
        dn += w0 + w1 + w2 + w3;
    }
    // fold the 4 edge-groups together; dn rides the same 2 stages
    #pragma unroll
    for (int off = 32; off >= 16; off >>= 1) {
        acc[0] += __shfl_xor(acc[0], off);
        acc[1] += __shfl_xor(acc[1], off);
        acc[2] += __shfl_xor(acc[2], off);
        acc[3] += __shfl_xor(acc[3], off);
        dn     += __shfl_xor(dn, off);
    }
    float inv = (deg > 0) ? 1.f / dn : 0.f;
    f32x4 a4 = acc * inv;

    // epilogue stores from lanes 0-15 (l16-chunk layout, no transpose)
    if (lane < 16) {
        f32x4 o4;
        if (k == 0) {
            f32x4 f4 = ((const f32x4*)features_f32)[node * 16 + l16];
            o4 = temp[0] * f4;
        } else {
            o4 = ((const f32x4*)out)[node * 16 + l16];
        }
        o4 += temp[k + 1] * a4;
        ((f32x4*)out)[node * 16 + l16] = o4;
        if (!last) {
            u16x4 ub = {f2bf(a4[0]), f2bf(a4[1]), f2bf(a4[2]), f2bf(a4[3])};
            ((u16x4*)feats_out_bf)[node * 16 + l16] = ub;
        }
    }
    if (!last) {  // fused s/t for next hop (fp32 accumulator, pre-rounding)
        f32x4 aw_s4 = ((const f32x4*)attn_w)[l16];
        f32x4 aw_t4 = ((const f32x4*)attn_w)[16 + l16];
        float sp = a4[0] * aw_s4[0] + a4[1] * aw_s4[1] + a4[2] * aw_s4[2] + a4[3] * aw_s4[3];
        float tq = a4[0] * aw_t4[0] + a4[1] * aw_t4[1] + a4[2] * aw_t4[2] + a4[3] * aw_t4[3];
        #pragma unroll
        for (int off = 1; off < 16; off <<= 1) {
            sp += __shfl_xor(sp, off);
            tq += __shfl_xor(tq, off);
        }
        if (lane == 0) { s_next[node] = sp; t_next[node] = tq; }
    }
}

extern "C" void kernel_launch(void* const* d_in, const int* in_sizes, int n_in,
                              void* d_out, int out_size, void* d_ws, size_t ws_size,
                              hipStream_t stream) {
    const float* features = (const float*)d_in[0];
    const int* src = (const int*)d_in[1];
    const int* dst = (const int*)d_in[2];
    const float* attn_w = (const float*)d_in[3];
    const float* attn_b = (const float*)d_in[4];
    const float* temp = (const float*)d_in[5];
    float* out = (float*)d_out;

    // workspace layout (~27 MB): s0/s1/t0/t1, cursor(=degree), ushort slotted
    // CSR, two bf16 feature buffers (ping-pong fbf0 -> fbfA -> fbf0).
    float* s0 = (float*)d_ws;                          // N
    float* s1 = s0 + N_NODES;                          // N
    float* t0 = s1 + N_NODES;                          // N
    float* t1 = t0 + N_NODES;                          // N
    unsigned* cursor = (unsigned*)(t1 + N_NODES);      // N (degree after scatter)
    unsigned short* csr_slot = (unsigned short*)(cursor + N_NODES);  // N*64 u16 (8 MB)
    unsigned short* fbf0 = csr_slot + (size_t)N_NODES * SLOT_CAP;    // N*DIM bf16
    unsigned short* fbfA = fbf0 + (size_t)N_NODES * DIM;             // N*DIM bf16

    const int NODE_BLOCKS = N_NODES / 4;     // 16384

    hipMemsetAsync(cursor, 0, N_NODES * sizeof(unsigned), stream);
    prep_scatter<<<PART_BLOCKS, 256, 0, stream>>>(features, attn_w, src, dst,
                                                  s0, t0, fbf0, cursor, csr_slot);

    // ---- 3 hops (bf16 gather buffers ping-pong) ----
    node_agg<<<NODE_BLOCKS, 256, 0, stream>>>(fbf0, features, s0, t0, cursor, csr_slot,
                                              attn_w, attn_b, temp, 0, 0,
                                              fbfA, s1, t1, out);
    node_agg<<<NODE_BLOCKS, 256, 0, stream>>>(fbfA, features, s1, t1, cursor, csr_slot,
                                              attn_w, attn_b, temp, 1, 0,
                                              fbf0, s0, t0, out);
    node_agg<<<NODE_BLOCKS, 256, 0, stream>>>(fbf0, features, s0, t0, cursor, csr_slot,
                                              attn_w, attn_b, temp, 2, 1,
                                              fbfA, s1, t1, out);
}